// Round 1
// baseline (172.093 us; speedup 1.0000x reference)
//
#include <hip/hip_runtime.h>
#include <hip/hip_bf16.h>

typedef __attribute__((ext_vector_type(4))) float  f32x4;
typedef __attribute__((ext_vector_type(8))) short  short8;
typedef __attribute__((ext_vector_type(4))) short  short4v;

__device__ __forceinline__ short f2bf(float f) {
  union { float f; unsigned u; } x; x.f = f;
  unsigned r = (x.u + 0x7FFFu + ((x.u >> 16) & 1u)) >> 16;
  return (short)r;
}

// ---------------- cast f32 -> bf16, vectorized x4 ----------------
__global__ __launch_bounds__(256) void k_cast(const float* __restrict__ in,
                                              short* __restrict__ out, int n4) {
  int i = blockIdx.x * 256 + threadIdx.x;
  if (i >= n4) return;
  f32x4 v = ((const f32x4*)in)[i];
  short4v s;
  s[0] = f2bf(v[0]); s[1] = f2bf(v[1]); s[2] = f2bf(v[2]); s[3] = f2bf(v[3]);
  ((short4v*)out)[i] = s;
}

// ---------------- pack w_q/w_k/w_v -> WqkvT bf16 [3072][1024] ----------------
// WqkvT[sel*1024 + h*64 + kd][e] = w_sel[e][h][kd]
__global__ __launch_bounds__(256) void k_pack(const float* __restrict__ wq,
                                              const float* __restrict__ wk,
                                              const float* __restrict__ wv,
                                              short* __restrict__ WT) {
  int nt = blockIdx.x;   // hk tile 0..15
  int et = blockIdx.y;   // e tile 0..15
  int sel = blockIdx.z;  // 0,1,2
  const float* w = sel == 0 ? wq : (sel == 1 ? wk : wv);
  __shared__ float tile[64][65];
  int tid = threadIdx.x;
  int cl = tid & 63, rw = tid >> 6;
#pragma unroll
  for (int j = 0; j < 16; ++j) {
    int el = j * 4 + rw;
    tile[el][cl] = w[(size_t)(et * 64 + el) * 1024 + nt * 64 + cl];
  }
  __syncthreads();
#pragma unroll
  for (int j = 0; j < 16; ++j) {
    int nl = j * 4 + rw;
    int n = sel * 1024 + nt * 64 + nl;
    WT[(size_t)n * 1024 + et * 64 + cl] = f2bf(tile[cl][nl]);
  }
}

// ---------------- GEMM C[M][N] = A[M][K] * B^T[N][K], bf16 in, f32 acc ----------------
// EPI==0: scatter Q(*0.125)/K/V bf16 -> [BH][2048][64]; EPI==1: f32 out row-major
template <int EPI>
__global__ __launch_bounds__(256) void k_gemm(const short* __restrict__ A,
                                              const short* __restrict__ B,
                                              short* __restrict__ Qo, short* __restrict__ Ko,
                                              short* __restrict__ Vo, float* __restrict__ out,
                                              int M, int N, int K) {
  __shared__ short As[128][40];
  __shared__ short Bs[128][40];
  int tid = threadIdx.x;
  int bm = blockIdx.y * 128, bn = blockIdx.x * 128;
  int wid = tid >> 6, lane = tid & 63;
  int wm = (wid >> 1) * 64, wn = (wid & 1) * 64;
  int lg = lane >> 4, lr = lane & 15;
  f32x4 acc[4][4] = {};

  int sr = tid >> 2, sc = tid & 3;
  const short* Ar0 = A + (size_t)(bm + sr) * K;
  const short* Ar1 = A + (size_t)(bm + sr + 64) * K;
  const short* Br0 = B + (size_t)(bn + sr) * K;
  const short* Br1 = B + (size_t)(bn + sr + 64) * K;

  short8 pa0 = *(const short8*)&Ar0[sc * 8];
  short8 pa1 = *(const short8*)&Ar1[sc * 8];
  short8 pb0 = *(const short8*)&Br0[sc * 8];
  short8 pb1 = *(const short8*)&Br1[sc * 8];

  int nk = K >> 5;
  for (int kt = 0; kt < nk; ++kt) {
    __syncthreads();
    *(short8*)&As[sr][sc * 8] = pa0;
    *(short8*)&As[sr + 64][sc * 8] = pa1;
    *(short8*)&Bs[sr][sc * 8] = pb0;
    *(short8*)&Bs[sr + 64][sc * 8] = pb1;
    if (kt + 1 < nk) {
      int ko = (kt + 1) * 32;
      pa0 = *(const short8*)&Ar0[ko + sc * 8];
      pa1 = *(const short8*)&Ar1[ko + sc * 8];
      pb0 = *(const short8*)&Br0[ko + sc * 8];
      pb1 = *(const short8*)&Br1[ko + sc * 8];
    }
    __syncthreads();
    short8 af[4], bf_[4];
#pragma unroll
    for (int mt = 0; mt < 4; ++mt)
      af[mt] = *(const short8*)&As[wm + mt * 16 + lr][lg * 8];
#pragma unroll
    for (int ntl = 0; ntl < 4; ++ntl)
      bf_[ntl] = *(const short8*)&Bs[wn + ntl * 16 + lr][lg * 8];
#pragma unroll
    for (int mt = 0; mt < 4; ++mt)
#pragma unroll
      for (int ntl = 0; ntl < 4; ++ntl)
        acc[mt][ntl] = __builtin_amdgcn_mfma_f32_16x16x32_bf16(af[mt], bf_[ntl], acc[mt][ntl], 0, 0, 0);
  }

#pragma unroll
  for (int mt = 0; mt < 4; ++mt)
#pragma unroll
    for (int ntl = 0; ntl < 4; ++ntl)
#pragma unroll
      for (int rr = 0; rr < 4; ++rr) {
        int m = bm + wm + mt * 16 + lg * 4 + rr;
        int n = bn + wn + ntl * 16 + lr;
        float val = acc[mt][ntl][rr];
        if (EPI == 0) {
          int b = m >> 11, s = m & 2047;
          int sel = n >> 10, hk = n & 1023;
          int h = hk >> 6, kd = hk & 63;
          size_t dst = ((size_t)(b * 16 + h) * 2048 + s) * 64 + kd;
          if (sel == 0) Qo[dst] = f2bf(val * 0.125f);
          else if (sel == 1) Ko[dst] = f2bf(val);
          else Vo[dst] = f2bf(val);
        } else {
          out[(size_t)m * 1024 + n] = val;
        }
      }
}

// ---------------- causal flash attention, bf16 MFMA ----------------
// Q,K,V: [32][2048][64] bf16 (Q pre-scaled by 1/8). O: [B=2][2048][H*64=1024] bf16
__global__ __launch_bounds__(256) void k_attn(const short* __restrict__ Q,
                                              const short* __restrict__ Kb,
                                              const short* __restrict__ Vb,
                                              short* __restrict__ O) {
  const int S = 2048;
  int bh = blockIdx.x;  // 0..31
  int qb = blockIdx.y;  // 0..31
  int tid = threadIdx.x, wid = tid >> 6, lane = tid & 63;
  int lg = lane >> 4, lr = lane & 15;
  __shared__ short Ks[64][72];
  __shared__ short Vt[64][72];
  __shared__ short Ps[4][16][72];

  const short* qbase = Q + ((size_t)bh * S + qb * 64 + wid * 16) * 64;
  short8 qf[2];
  qf[0] = *(const short8*)&qbase[lr * 64 + lg * 8];
  qf[1] = *(const short8*)&qbase[lr * 64 + 32 + lg * 8];

  float m_i[4], l_i[4];
  f32x4 aco[4];
#pragma unroll
  for (int rr = 0; rr < 4; ++rr) { m_i[rr] = -1e30f; l_i[rr] = 0.f; }
#pragma unroll
  for (int ntl = 0; ntl < 4; ++ntl) aco[ntl] = (f32x4){0.f, 0.f, 0.f, 0.f};

  int sr = tid >> 2, sc = tid & 3;
  const short* krow = Kb + ((size_t)bh * S + sr) * 64;
  const short* vrow = Vb + ((size_t)bh * S + sr) * 64;

  int ntile = qb + 1;
  for (int t = 0; t < ntile; ++t) {
    __syncthreads();
    size_t off = (size_t)t * 4096;
    short8 k0 = *(const short8*)&krow[off + sc * 8];
    short8 k1 = *(const short8*)&krow[off + 32 + sc * 8];
    short8 v0 = *(const short8*)&vrow[off + sc * 8];
    short8 v1 = *(const short8*)&vrow[off + 32 + sc * 8];
    *(short8*)&Ks[sr][sc * 8] = k0;
    *(short8*)&Ks[sr][sc * 8 + 32] = k1;
#pragma unroll
    for (int j = 0; j < 8; ++j) {
      Vt[sc * 8 + j][sr] = v0[j];
      Vt[sc * 8 + 32 + j][sr] = v1[j];
    }
    __syncthreads();

    // S = Q K^T  (16 q-rows x 64 kv-cols)
    f32x4 sa[4];
#pragma unroll
    for (int ntl = 0; ntl < 4; ++ntl) sa[ntl] = (f32x4){0.f, 0.f, 0.f, 0.f};
#pragma unroll
    for (int ntl = 0; ntl < 4; ++ntl)
#pragma unroll
      for (int ks = 0; ks < 2; ++ks) {
        short8 kf = *(const short8*)&Ks[ntl * 16 + lr][ks * 32 + lg * 8];
        sa[ntl] = __builtin_amdgcn_mfma_f32_16x16x32_bf16(qf[ks], kf, sa[ntl], 0, 0, 0);
      }

    // online softmax
    int qpos0 = qb * 64 + wid * 16 + lg * 4;
#pragma unroll
    for (int rr = 0; rr < 4; ++rr) {
      float mx = -1e30f;
#pragma unroll
      for (int ntl = 0; ntl < 4; ++ntl) {
        int kvpos = t * 64 + ntl * 16 + lr;
        float s = sa[ntl][rr];
        if (kvpos > qpos0 + rr) s = -1e30f;
        sa[ntl][rr] = s;
        mx = fmaxf(mx, s);
      }
      mx = fmaxf(mx, __shfl_xor(mx, 1, 16));
      mx = fmaxf(mx, __shfl_xor(mx, 2, 16));
      mx = fmaxf(mx, __shfl_xor(mx, 4, 16));
      mx = fmaxf(mx, __shfl_xor(mx, 8, 16));
      float mnew = fmaxf(m_i[rr], mx);
      float alpha = __expf(m_i[rr] - mnew);
      m_i[rr] = mnew;
      float rsum = 0.f;
#pragma unroll
      for (int ntl = 0; ntl < 4; ++ntl) {
        float p = __expf(sa[ntl][rr] - mnew);
        rsum += p;
        Ps[wid][lg * 4 + rr][ntl * 16 + lr] = f2bf(p);
      }
      rsum += __shfl_xor(rsum, 1, 16);
      rsum += __shfl_xor(rsum, 2, 16);
      rsum += __shfl_xor(rsum, 4, 16);
      rsum += __shfl_xor(rsum, 8, 16);
      l_i[rr] = l_i[rr] * alpha + rsum;
#pragma unroll
      for (int ntl = 0; ntl < 4; ++ntl) aco[ntl][rr] *= alpha;
    }
    asm volatile("s_waitcnt lgkmcnt(0)" ::: "memory");
    __builtin_amdgcn_sched_barrier(0);

    // O += P V
#pragma unroll
    for (int ks = 0; ks < 2; ++ks) {
      short8 pf = *(const short8*)&Ps[wid][lr][ks * 32 + lg * 8];
#pragma unroll
      for (int ntl = 0; ntl < 4; ++ntl) {
        short8 vf = *(const short8*)&Vt[ntl * 16 + lr][ks * 32 + lg * 8];
        aco[ntl] = __builtin_amdgcn_mfma_f32_16x16x32_bf16(pf, vf, aco[ntl], 0, 0, 0);
      }
    }
  }

  int b = bh >> 4, h = bh & 15;
#pragma unroll
  for (int ntl = 0; ntl < 4; ++ntl)
#pragma unroll
    for (int rr = 0; rr < 4; ++rr) {
      int qp = qb * 64 + wid * 16 + lg * 4 + rr;
      float o = aco[ntl][rr] / l_i[rr];
      O[((size_t)b * 2048 + qp) * 1024 + h * 64 + ntl * 16 + lr] = f2bf(o);
    }
}

extern "C" void kernel_launch(void* const* d_in, const int* in_sizes, int n_in,
                              void* d_out, int out_size, void* d_ws, size_t ws_size,
                              hipStream_t stream) {
  const float* x  = (const float*)d_in[0];
  const float* wq = (const float*)d_in[1];
  const float* wk = (const float*)d_in[2];
  const float* wv = (const float*)d_in[3];
  const float* wo = (const float*)d_in[4];
  float* out = (float*)d_out;
  char* ws = (char*)d_ws;

  short* x_bf  = (short*)(ws);                       // 8 MB
  short* WqkvT = (short*)(ws + ((size_t)8 << 20));   // 6 MB
  short* wo_bf = (short*)(ws + ((size_t)14 << 20));  // 2 MB
  short* Qb    = (short*)(ws + ((size_t)16 << 20));  // 8 MB
  short* Kb    = (short*)(ws + ((size_t)24 << 20));  // 8 MB
  short* Vb    = (short*)(ws + ((size_t)32 << 20));  // 8 MB
  short* Ob    = (short*)(ws + ((size_t)40 << 20));  // 8 MB

  k_cast<<<4096, 256, 0, stream>>>(x, x_bf, 1048576);
  k_cast<<<1024, 256, 0, stream>>>(wo, wo_bf, 262144);
  k_pack<<<dim3(16, 16, 3), 256, 0, stream>>>(wq, wk, wv, WqkvT);
  k_gemm<0><<<dim3(24, 32), 256, 0, stream>>>(x_bf, WqkvT, Qb, Kb, Vb, nullptr, 4096, 3072, 1024);
  k_attn<<<dim3(32, 32), 256, 0, stream>>>(Qb, Kb, Vb, Ob);
  k_gemm<1><<<dim3(8, 32), 256, 0, stream>>>(Ob, wo_bf, nullptr, nullptr, nullptr, out, 4096, 1024, 1024);
}

// Round 2
// 160.225 us; speedup vs baseline: 1.0741x; 1.0741x over previous
//
#include <hip/hip_runtime.h>
#include <hip/hip_bf16.h>

typedef __attribute__((ext_vector_type(4))) float  f32x4;
typedef __attribute__((ext_vector_type(8))) short  short8;
typedef __attribute__((ext_vector_type(4))) short  short4v;

__device__ __forceinline__ short f2bf(float f) {
  union { float f; unsigned u; } x; x.f = f;
  unsigned r = (x.u + 0x7FFFu + ((x.u >> 16) & 1u)) >> 16;
  return (short)r;
}

// ---------------- cast f32 -> bf16, vectorized x4 ----------------
__global__ __launch_bounds__(256) void k_cast(const float* __restrict__ in,
                                              short* __restrict__ out, int n4) {
  int i = blockIdx.x * 256 + threadIdx.x;
  if (i >= n4) return;
  f32x4 v = ((const f32x4*)in)[i];
  short4v s;
  s[0] = f2bf(v[0]); s[1] = f2bf(v[1]); s[2] = f2bf(v[2]); s[3] = f2bf(v[3]);
  ((short4v*)out)[i] = s;
}

// ---------------- pack w_q/w_k/w_v -> WqkvT bf16 [3072][1024] ----------------
// WqkvT[sel*1024 + h*64 + kd][e] = w_sel[e][h][kd]
__global__ __launch_bounds__(256) void k_pack(const float* __restrict__ wq,
                                              const float* __restrict__ wk,
                                              const float* __restrict__ wv,
                                              short* __restrict__ WT) {
  int nt = blockIdx.x;   // hk tile 0..15
  int et = blockIdx.y;   // e tile 0..15
  int sel = blockIdx.z;  // 0,1,2
  const float* w = sel == 0 ? wq : (sel == 1 ? wk : wv);
  __shared__ float tile[64][65];
  int tid = threadIdx.x;
  int cl = tid & 63, rw = tid >> 6;
#pragma unroll
  for (int j = 0; j < 16; ++j) {
    int el = j * 4 + rw;
    tile[el][cl] = w[(size_t)(et * 64 + el) * 1024 + nt * 64 + cl];
  }
  __syncthreads();
#pragma unroll
  for (int j = 0; j < 16; ++j) {
    int nl = j * 4 + rw;
    int n = sel * 1024 + nt * 64 + nl;
    WT[(size_t)n * 1024 + et * 64 + cl] = f2bf(tile[cl][nl]);
  }
}

// ---------------- GEMM C[M][N] = A[M][K] * B^T[N][K], bf16 in, f32 acc ----------------
// EPI==0: scatter Q(*0.125)/K/V bf16 -> [BH][2048][64]; EPI==1: f32 out row-major
template <int EPI>
__global__ __launch_bounds__(256) void k_gemm(const short* __restrict__ A,
                                              const short* __restrict__ B,
                                              short* __restrict__ Qo, short* __restrict__ Ko,
                                              short* __restrict__ Vo, float* __restrict__ out,
                                              int M, int N, int K) {
  __shared__ short As[128][40];
  __shared__ short Bs[128][40];
  int tid = threadIdx.x;
  int bm = blockIdx.y * 128, bn = blockIdx.x * 128;
  int wid = tid >> 6, lane = tid & 63;
  int wm = (wid >> 1) * 64, wn = (wid & 1) * 64;
  int lg = lane >> 4, lr = lane & 15;
  f32x4 acc[4][4] = {};

  int sr = tid >> 2, sc = tid & 3;
  const short* Ar0 = A + (size_t)(bm + sr) * K;
  const short* Ar1 = A + (size_t)(bm + sr + 64) * K;
  const short* Br0 = B + (size_t)(bn + sr) * K;
  const short* Br1 = B + (size_t)(bn + sr + 64) * K;

  short8 pa0 = *(const short8*)&Ar0[sc * 8];
  short8 pa1 = *(const short8*)&Ar1[sc * 8];
  short8 pb0 = *(const short8*)&Br0[sc * 8];
  short8 pb1 = *(const short8*)&Br1[sc * 8];

  int nk = K >> 5;
  for (int kt = 0; kt < nk; ++kt) {
    __syncthreads();
    *(short8*)&As[sr][sc * 8] = pa0;
    *(short8*)&As[sr + 64][sc * 8] = pa1;
    *(short8*)&Bs[sr][sc * 8] = pb0;
    *(short8*)&Bs[sr + 64][sc * 8] = pb1;
    if (kt + 1 < nk) {
      int ko = (kt + 1) * 32;
      pa0 = *(const short8*)&Ar0[ko + sc * 8];
      pa1 = *(const short8*)&Ar1[ko + sc * 8];
      pb0 = *(const short8*)&Br0[ko + sc * 8];
      pb1 = *(const short8*)&Br1[ko + sc * 8];
    }
    __syncthreads();
    short8 af[4], bf_[4];
#pragma unroll
    for (int mt = 0; mt < 4; ++mt)
      af[mt] = *(const short8*)&As[wm + mt * 16 + lr][lg * 8];
#pragma unroll
    for (int ntl = 0; ntl < 4; ++ntl)
      bf_[ntl] = *(const short8*)&Bs[wn + ntl * 16 + lr][lg * 8];
#pragma unroll
    for (int mt = 0; mt < 4; ++mt)
#pragma unroll
      for (int ntl = 0; ntl < 4; ++ntl)
        acc[mt][ntl] = __builtin_amdgcn_mfma_f32_16x16x32_bf16(af[mt], bf_[ntl], acc[mt][ntl], 0, 0, 0);
  }

#pragma unroll
  for (int mt = 0; mt < 4; ++mt)
#pragma unroll
    for (int ntl = 0; ntl < 4; ++ntl)
#pragma unroll
      for (int rr = 0; rr < 4; ++rr) {
        int m = bm + wm + mt * 16 + lg * 4 + rr;
        int n = bn + wn + ntl * 16 + lr;
        float val = acc[mt][ntl][rr];
        if (EPI == 0) {
          int b = m >> 11, s = m & 2047;
          int sel = n >> 10, hk = n & 1023;
          int h = hk >> 6, kd = hk & 63;
          size_t dst = ((size_t)(b * 16 + h) * 2048 + s) * 64 + kd;
          if (sel == 0) Qo[dst] = f2bf(val * 0.125f);
          else if (sel == 1) Ko[dst] = f2bf(val);
          else Vo[dst] = f2bf(val);
        } else {
          out[(size_t)m * 1024 + n] = val;
        }
      }
}

// ---------------- causal flash attention, bf16 MFMA ----------------
// Q,K,V: [32][2048][64] bf16 (Q pre-scaled by 1/8). O: [B=2][2048][H*64=1024] bf16
__global__ __launch_bounds__(256) void k_attn(const short* __restrict__ Q,
                                              const short* __restrict__ Kb,
                                              const short* __restrict__ Vb,
                                              short* __restrict__ O) {
  const int S = 2048;
  int bh = blockIdx.x;  // 0..31
  // per-CU load-balance remap: CU resident set {y, y+8, y+16, y+24} sums to 66 tiles
  {
  }
  int y = blockIdx.y;
  int g = y & 7, s4 = y >> 3;
  int qb = (s4 & 1) ? (s4 * 8 + 7 - g) : (s4 * 8 + g);

  int tid = threadIdx.x, wid = tid >> 6, lane = tid & 63;
  int lg = lane >> 4, lr = lane & 15;
  // Ks: XOR-swizzled linear [64][64]  (16B block index ^= row&7)
  __shared__ short Ks[64 * 64];
  // Vt: transposed [d=64][kv=64], stride 66 shorts (132B => 33 dwords, row enters bank idx)
  __shared__ short Vt[64 * 66];
  __shared__ short Ps[4][16][72];

  const short* qbase = Q + ((size_t)bh * S + qb * 64 + wid * 16) * 64;
  short8 qf[2];
  qf[0] = *(const short8*)&qbase[lr * 64 + lg * 8];
  qf[1] = *(const short8*)&qbase[lr * 64 + 32 + lg * 8];

  float m_i[4], l_i[4];
  f32x4 aco[4];
#pragma unroll
  for (int rr = 0; rr < 4; ++rr) { m_i[rr] = -1e30f; l_i[rr] = 0.f; }
#pragma unroll
  for (int ntl = 0; ntl < 4; ++ntl) aco[ntl] = (f32x4){0.f, 0.f, 0.f, 0.f};

  int sr = tid >> 2, sc = tid & 3;
  const short* krow = Kb + ((size_t)bh * S + sr) * 64;
  const short* vrow = Vb + ((size_t)bh * S + sr) * 64;

  int ntile = qb + 1;
  // prefetch tile 0
  short8 k0 = *(const short8*)&krow[sc * 8];
  short8 k1 = *(const short8*)&krow[32 + sc * 8];
  short8 v0 = *(const short8*)&vrow[sc * 8];
  short8 v1 = *(const short8*)&vrow[32 + sc * 8];

  for (int t = 0; t < ntile; ++t) {
    __syncthreads();
    // stage current tile from regs
    *(short8*)&Ks[sr * 64 + ((sc ^ (sr & 7)) * 8)] = k0;
    *(short8*)&Ks[sr * 64 + (((sc + 4) ^ (sr & 7)) * 8)] = k1;
#pragma unroll
    for (int j = 0; j < 8; ++j) {
      Vt[(sc * 8 + j) * 66 + sr] = v0[j];
      Vt[(32 + sc * 8 + j) * 66 + sr] = v1[j];
    }
    // prefetch next tile (latency hidden under compute)
    if (t + 1 < ntile) {
      size_t off = (size_t)(t + 1) * 4096;
      k0 = *(const short8*)&krow[off + sc * 8];
      k1 = *(const short8*)&krow[off + 32 + sc * 8];
      v0 = *(const short8*)&vrow[off + sc * 8];
      v1 = *(const short8*)&vrow[off + 32 + sc * 8];
    }
    __syncthreads();

    // S = Q K^T  (16 q-rows x 64 kv-cols)
    f32x4 sa[4];
#pragma unroll
    for (int ntl = 0; ntl < 4; ++ntl) sa[ntl] = (f32x4){0.f, 0.f, 0.f, 0.f};
#pragma unroll
    for (int ntl = 0; ntl < 4; ++ntl)
#pragma unroll
      for (int ks = 0; ks < 2; ++ks) {
        short8 kf = *(const short8*)&Ks[(ntl * 16 + lr) * 64 + (((ks * 4 + lg) ^ (lr & 7)) * 8)];
        sa[ntl] = __builtin_amdgcn_mfma_f32_16x16x32_bf16(qf[ks], kf, sa[ntl], 0, 0, 0);
      }

    // online softmax (only diagonal tile needs the causal mask)
    int qpos0 = qb * 64 + wid * 16 + lg * 4;
    bool diag = (t == qb);
#pragma unroll
    for (int rr = 0; rr < 4; ++rr) {
      float mx = -1e30f;
      if (diag) {
#pragma unroll
        for (int ntl = 0; ntl < 4; ++ntl) {
          int kvpos = t * 64 + ntl * 16 + lr;
          float s = sa[ntl][rr];
          if (kvpos > qpos0 + rr) s = -1e30f;
          sa[ntl][rr] = s;
          mx = fmaxf(mx, s);
        }
      } else {
#pragma unroll
        for (int ntl = 0; ntl < 4; ++ntl) mx = fmaxf(mx, sa[ntl][rr]);
      }
      mx = fmaxf(mx, __shfl_xor(mx, 1, 16));
      mx = fmaxf(mx, __shfl_xor(mx, 2, 16));
      mx = fmaxf(mx, __shfl_xor(mx, 4, 16));
      mx = fmaxf(mx, __shfl_xor(mx, 8, 16));
      float mnew = fmaxf(m_i[rr], mx);
      float alpha = __expf(m_i[rr] - mnew);
      m_i[rr] = mnew;
      float rsum = 0.f;
#pragma unroll
      for (int ntl = 0; ntl < 4; ++ntl) {
        float p = __expf(sa[ntl][rr] - mnew);
        rsum += p;
        Ps[wid][lg * 4 + rr][ntl * 16 + lr] = f2bf(p);
      }
      rsum += __shfl_xor(rsum, 1, 16);
      rsum += __shfl_xor(rsum, 2, 16);
      rsum += __shfl_xor(rsum, 4, 16);
      rsum += __shfl_xor(rsum, 8, 16);
      l_i[rr] = l_i[rr] * alpha + rsum;
#pragma unroll
      for (int ntl = 0; ntl < 4; ++ntl) aco[ntl][rr] *= alpha;
    }
    asm volatile("s_waitcnt lgkmcnt(0)" ::: "memory");
    __builtin_amdgcn_sched_barrier(0);

    // O += P V
#pragma unroll
    for (int ks = 0; ks < 2; ++ks) {
      short8 pf = *(const short8*)&Ps[wid][lr][ks * 32 + lg * 8];
#pragma unroll
      for (int ntl = 0; ntl < 4; ++ntl) {
        short8 vf = *(const short8*)&Vt[(ntl * 16 + lr) * 66 + ks * 32 + lg * 8];
        aco[ntl] = __builtin_amdgcn_mfma_f32_16x16x32_bf16(pf, vf, aco[ntl], 0, 0, 0);
      }
    }
  }

  int b = bh >> 4, h = bh & 15;
#pragma unroll
  for (int ntl = 0; ntl < 4; ++ntl)
#pragma unroll
    for (int rr = 0; rr < 4; ++rr) {
      int qp = qb * 64 + wid * 16 + lg * 4 + rr;
      float o = aco[ntl][rr] / l_i[rr];
      O[((size_t)b * 2048 + qp) * 1024 + h * 64 + ntl * 16 + lr] = f2bf(o);
    }
}

extern "C" void kernel_launch(void* const* d_in, const int* in_sizes, int n_in,
                              void* d_out, int out_size, void* d_ws, size_t ws_size,
                              hipStream_t stream) {
  const float* x  = (const float*)d_in[0];
  const float* wq = (const float*)d_in[1];
  const float* wk = (const float*)d_in[2];
  const float* wv = (const float*)d_in[3];
  const float* wo = (const float*)d_in[4];
  float* out = (float*)d_out;
  char* ws = (char*)d_ws;

  short* x_bf  = (short*)(ws);                       // 8 MB
  short* WqkvT = (short*)(ws + ((size_t)8 << 20));   // 6 MB
  short* wo_bf = (short*)(ws + ((size_t)14 << 20));  // 2 MB
  short* Qb    = (short*)(ws + ((size_t)16 << 20));  // 8 MB
  short* Kb    = (short*)(ws + ((size_t)24 << 20));  // 8 MB
  short* Vb    = (short*)(ws + ((size_t)32 << 20));  // 8 MB
  short* Ob    = (short*)(ws + ((size_t)40 << 20));  // 8 MB

  k_cast<<<4096, 256, 0, stream>>>(x, x_bf, 1048576);
  k_cast<<<1024, 256, 0, stream>>>(wo, wo_bf, 262144);
  k_pack<<<dim3(16, 16, 3), 256, 0, stream>>>(wq, wk, wv, WqkvT);
  k_gemm<0><<<dim3(24, 32), 256, 0, stream>>>(x_bf, WqkvT, Qb, Kb, Vb, nullptr, 4096, 3072, 1024);
  k_attn<<<dim3(32, 32), 256, 0, stream>>>(Qb, Kb, Vb, Ob);
  k_gemm<1><<<dim3(8, 32), 256, 0, stream>>>(Ob, wo_bf, nullptr, nullptr, nullptr, out, 4096, 1024, 1024);
}

// Round 3
// 149.247 us; speedup vs baseline: 1.1531x; 1.0736x over previous
//
#include <hip/hip_runtime.h>
#include <hip/hip_bf16.h>

typedef __attribute__((ext_vector_type(4)))  float f32x4;
typedef __attribute__((ext_vector_type(16))) float f32x16;
typedef __attribute__((ext_vector_type(8)))  short short8;
typedef __attribute__((ext_vector_type(4)))  short short4v;

__device__ __forceinline__ short f2bf(float f) {
  union { float f; unsigned u; } x; x.f = f;
  unsigned r = (x.u + 0x7FFFu + ((x.u >> 16) & 1u)) >> 16;
  return (short)r;
}
__device__ __forceinline__ unsigned pk2(float lo, float hi) {
  return (unsigned)(unsigned short)f2bf(lo) | ((unsigned)(unsigned short)f2bf(hi) << 16);
}

// ---------------- cast f32 -> bf16, vectorized x4 ----------------
__global__ __launch_bounds__(256) void k_cast(const float* __restrict__ in,
                                              short* __restrict__ out, int n4) {
  int i = blockIdx.x * 256 + threadIdx.x;
  if (i >= n4) return;
  f32x4 v = ((const f32x4*)in)[i];
  short4v s;
  s[0] = f2bf(v[0]); s[1] = f2bf(v[1]); s[2] = f2bf(v[2]); s[3] = f2bf(v[3]);
  ((short4v*)out)[i] = s;
}

// ---------------- pack w_q/w_k/w_v -> WqkvT bf16 [3072][1024] ----------------
__global__ __launch_bounds__(256) void k_pack(const float* __restrict__ wq,
                                              const float* __restrict__ wk,
                                              const float* __restrict__ wv,
                                              short* __restrict__ WT) {
  int nt = blockIdx.x, et = blockIdx.y, sel = blockIdx.z;
  const float* w = sel == 0 ? wq : (sel == 1 ? wk : wv);
  __shared__ float tile[64][65];
  int tid = threadIdx.x;
  int cl = tid & 63, rw = tid >> 6;
#pragma unroll
  for (int j = 0; j < 16; ++j) {
    int el = j * 4 + rw;
    tile[el][cl] = w[(size_t)(et * 64 + el) * 1024 + nt * 64 + cl];
  }
  __syncthreads();
#pragma unroll
  for (int j = 0; j < 16; ++j) {
    int nl = j * 4 + rw;
    int n = sel * 1024 + nt * 64 + nl;
    WT[(size_t)n * 1024 + et * 64 + cl] = f2bf(tile[cl][nl]);
  }
}

// ---------------- GEMM C[M][N] = A[M][K] * B^T[N][K], bf16 in, f32 acc ----------------
// EPI==0: scatter Q(*0.125)/K -> [BH][2048][64], V -> V^T [BH][64][2048]; EPI==1: f32 out
template <int EPI>
__global__ __launch_bounds__(256) void k_gemm(const short* __restrict__ A,
                                              const short* __restrict__ B,
                                              short* __restrict__ Qo, short* __restrict__ Ko,
                                              short* __restrict__ Vo, float* __restrict__ out,
                                              int M, int N, int K) {
  __shared__ short As[128][40];
  __shared__ short Bs[128][40];
  int tid = threadIdx.x;
  int bm = blockIdx.y * 128, bn = blockIdx.x * 128;
  int wid = tid >> 6, lane = tid & 63;
  int wm = (wid >> 1) * 64, wn = (wid & 1) * 64;
  int lg = lane >> 4, lr = lane & 15;
  f32x4 acc[4][4] = {};

  int sr = tid >> 2, sc = tid & 3;
  const short* Ar0 = A + (size_t)(bm + sr) * K;
  const short* Ar1 = A + (size_t)(bm + sr + 64) * K;
  const short* Br0 = B + (size_t)(bn + sr) * K;
  const short* Br1 = B + (size_t)(bn + sr + 64) * K;

  short8 pa0 = *(const short8*)&Ar0[sc * 8];
  short8 pa1 = *(const short8*)&Ar1[sc * 8];
  short8 pb0 = *(const short8*)&Br0[sc * 8];
  short8 pb1 = *(const short8*)&Br1[sc * 8];

  int nk = K >> 5;
  for (int kt = 0; kt < nk; ++kt) {
    __syncthreads();
    *(short8*)&As[sr][sc * 8] = pa0;
    *(short8*)&As[sr + 64][sc * 8] = pa1;
    *(short8*)&Bs[sr][sc * 8] = pb0;
    *(short8*)&Bs[sr + 64][sc * 8] = pb1;
    if (kt + 1 < nk) {
      int ko = (kt + 1) * 32;
      pa0 = *(const short8*)&Ar0[ko + sc * 8];
      pa1 = *(const short8*)&Ar1[ko + sc * 8];
      pb0 = *(const short8*)&Br0[ko + sc * 8];
      pb1 = *(const short8*)&Br1[ko + sc * 8];
    }
    __syncthreads();
    short8 af[4], bf_[4];
#pragma unroll
    for (int mt = 0; mt < 4; ++mt)
      af[mt] = *(const short8*)&As[wm + mt * 16 + lr][lg * 8];
#pragma unroll
    for (int ntl = 0; ntl < 4; ++ntl)
      bf_[ntl] = *(const short8*)&Bs[wn + ntl * 16 + lr][lg * 8];
#pragma unroll
    for (int mt = 0; mt < 4; ++mt)
#pragma unroll
      for (int ntl = 0; ntl < 4; ++ntl)
        acc[mt][ntl] = __builtin_amdgcn_mfma_f32_16x16x32_bf16(af[mt], bf_[ntl], acc[mt][ntl], 0, 0, 0);
  }

#pragma unroll
  for (int mt = 0; mt < 4; ++mt)
#pragma unroll
    for (int ntl = 0; ntl < 4; ++ntl)
#pragma unroll
      for (int rr = 0; rr < 4; ++rr) {
        int m = bm + wm + mt * 16 + lg * 4 + rr;
        int n = bn + wn + ntl * 16 + lr;
        float val = acc[mt][ntl][rr];
        if (EPI == 0) {
          int b = m >> 11, s = m & 2047;
          int sel = n >> 10, hk = n & 1023;
          int h = hk >> 6, kd = hk & 63;
          if (sel == 0) Qo[((size_t)(b * 16 + h) * 2048 + s) * 64 + kd] = f2bf(val * 0.125f);
          else if (sel == 1) Ko[((size_t)(b * 16 + h) * 2048 + s) * 64 + kd] = f2bf(val);
          else Vo[((size_t)(b * 16 + h) * 64 + kd) * 2048 + s] = f2bf(val);  // V^T
        } else {
          out[(size_t)m * 1024 + n] = val;
        }
      }
}

// ---------------- causal flash attention: swapped-operand 32x32x16, LDS-free ----------------
// Q,K: [32][2048][64] bf16 (Q pre-scaled 1/8). VT: [32][64][2048]. O: [2][2048][1024] bf16.
// Each wave owns 32 q-rows; block waves = {2a, 2a+1, 63-2a, 62-2a} -> uniform 130 tiles/block.
__global__ __launch_bounds__(256) void k_attn(const short* __restrict__ Q,
                                              const short* __restrict__ K,
                                              const short* __restrict__ VT,
                                              short* __restrict__ O) {
  const int S = 2048;
  int bh = blockIdx.x, a = blockIdx.y;
  int wid = threadIdx.x >> 6, lane = threadIdx.x & 63;
  int qw = (wid & 2) ? (63 - 2 * a - (wid & 1)) : (2 * a + (wid & 1));
  int q0 = qw * 32;
  int hi = lane >> 5, ln = lane & 31;
  int q_g = q0 + ln;

  const short* Qb = Q + (size_t)bh * S * 64;
  const short* Kb = K + (size_t)bh * S * 64;
  const short* Vb = VT + (size_t)bh * 64 * S;

  // Q fragments: B[k=d][col=q]: 8 consecutive d for own q  (4 k-steps of 16)
  short8 qf[4];
#pragma unroll
  for (int ds = 0; ds < 4; ++ds)
    qf[ds] = *(const short8*)&Qb[(size_t)q_g * 64 + ds * 16 + hi * 8];

  f32x16 acoA = {}, acoB = {};
  float m = -1e30f, l = 0.f;

  int ntile = qw + 1;
  // K fragments for tile 0: A[row=kv][k=d]
  short8 kc[4], kn[4];
#pragma unroll
  for (int ds = 0; ds < 4; ++ds)
    kc[ds] = *(const short8*)&Kb[(size_t)ln * 64 + ds * 16 + hi * 8];

  for (int t = 0; t < ntile; ++t) {
    // V^T fragments: A[row=d][k=kv]; chunk c: d=32c+ln, step s: kv=t*32+16s+hi*8
    const size_t vro = (size_t)ln * S + t * 32 + hi * 8;
    short8 v00 = *(const short8*)&Vb[vro];
    short8 v01 = *(const short8*)&Vb[vro + 16];
    short8 v10 = *(const short8*)&Vb[vro + (size_t)32 * S];
    short8 v11 = *(const short8*)&Vb[vro + (size_t)32 * S + 16];
    if (t + 1 < ntile) {
#pragma unroll
      for (int ds = 0; ds < 4; ++ds)
        kn[ds] = *(const short8*)&Kb[(size_t)((t + 1) * 32 + ln) * 64 + ds * 16 + hi * 8];
    }

    // S[kv][q] = K Q^T : lane holds 16 kv values for its own q
    f32x16 sa = {};
#pragma unroll
    for (int ds = 0; ds < 4; ++ds)
      sa = __builtin_amdgcn_mfma_f32_32x32x16_bf16(kc[ds], qf[ds], sa, 0, 0, 0);

    if (t == qw) {  // only the diagonal tile needs the causal mask
#pragma unroll
      for (int r = 0; r < 16; ++r) {
        int kv_g = t * 32 + (r & 3) + 8 * (r >> 2) + 4 * hi;
        if (kv_g > q_g) sa[r] = -1e30f;
      }
    }

    // row max: in-register tree + ONE cross-lane shfl
    float x0 = fmaxf(sa[0], sa[1]),  x1 = fmaxf(sa[2], sa[3]);
    float x2 = fmaxf(sa[4], sa[5]),  x3 = fmaxf(sa[6], sa[7]);
    float x4 = fmaxf(sa[8], sa[9]),  x5 = fmaxf(sa[10], sa[11]);
    float x6 = fmaxf(sa[12], sa[13]), x7 = fmaxf(sa[14], sa[15]);
    x0 = fmaxf(x0, x1); x2 = fmaxf(x2, x3); x4 = fmaxf(x4, x5); x6 = fmaxf(x6, x7);
    x0 = fmaxf(x0, x2); x4 = fmaxf(x4, x6);
    float mx = fmaxf(x0, x4);
    mx = fmaxf(mx, __shfl_xor(mx, 32));

    float mnew = fmaxf(m, mx);
    float alpha = __expf(m - mnew);
    m = mnew;

    float p[16];
#pragma unroll
    for (int r = 0; r < 16; ++r) p[r] = __expf(sa[r] - mnew);
    float s0 = (p[0] + p[1]) + (p[2] + p[3]);
    float s1 = (p[4] + p[5]) + (p[6] + p[7]);
    float s2 = (p[8] + p[9]) + (p[10] + p[11]);
    float s3 = (p[12] + p[13]) + (p[14] + p[15]);
    float rsum = (s0 + s1) + (s2 + s3);
    rsum += __shfl_xor(rsum, 32);
    l = l * alpha + rsum;
    acoA *= alpha;
    acoB *= alpha;

    // assemble P^T fragments (B[k=kv][col=q]) via pack + lane^32 exchange
#pragma unroll
    for (int s = 0; s < 2; ++s) {
      unsigned c0 = pk2(p[8 * s + 0], p[8 * s + 1]);
      unsigned c1 = pk2(p[8 * s + 2], p[8 * s + 3]);
      unsigned c2 = pk2(p[8 * s + 4], p[8 * s + 5]);
      unsigned c3 = pk2(p[8 * s + 6], p[8 * s + 7]);
      unsigned pc0 = (unsigned)__shfl_xor((int)c0, 32);
      unsigned pc1 = (unsigned)__shfl_xor((int)c1, 32);
      unsigned pc2 = (unsigned)__shfl_xor((int)c2, 32);
      unsigned pc3 = (unsigned)__shfl_xor((int)c3, 32);
      union { unsigned u[4]; short8 v; } pb;
      pb.u[0] = hi ? pc2 : c0;
      pb.u[1] = hi ? pc3 : c1;
      pb.u[2] = hi ? c2 : pc0;
      pb.u[3] = hi ? c3 : pc1;
      if (s == 0) {
        acoA = __builtin_amdgcn_mfma_f32_32x32x16_bf16(v00, pb.v, acoA, 0, 0, 0);
        acoB = __builtin_amdgcn_mfma_f32_32x32x16_bf16(v10, pb.v, acoB, 0, 0, 0);
      } else {
        acoA = __builtin_amdgcn_mfma_f32_32x32x16_bf16(v01, pb.v, acoA, 0, 0, 0);
        acoB = __builtin_amdgcn_mfma_f32_32x32x16_bf16(v11, pb.v, acoB, 0, 0, 0);
      }
    }
#pragma unroll
    for (int ds = 0; ds < 4; ++ds) kc[ds] = kn[ds];
  }

  // O[d][q] accumulators: lane-local q, d = (r&3)+8*(r>>2)+4*hi (+32 for acoB)
  float rl = 1.f / l;
  int b = bh >> 4, h = bh & 15;
  size_t obase = ((size_t)b * 2048 + q_g) * 1024 + h * 64;
#pragma unroll
  for (int g = 0; g < 4; ++g) {
    int d0 = 8 * g + 4 * hi;
    unsigned uA0 = pk2(acoA[4 * g] * rl, acoA[4 * g + 1] * rl);
    unsigned uA1 = pk2(acoA[4 * g + 2] * rl, acoA[4 * g + 3] * rl);
    unsigned uB0 = pk2(acoB[4 * g] * rl, acoB[4 * g + 1] * rl);
    unsigned uB1 = pk2(acoB[4 * g + 2] * rl, acoB[4 * g + 3] * rl);
    *(unsigned*)&O[obase + d0] = uA0;
    *(unsigned*)&O[obase + d0 + 2] = uA1;
    *(unsigned*)&O[obase + 32 + d0] = uB0;
    *(unsigned*)&O[obase + 32 + d0 + 2] = uB1;
  }
}

extern "C" void kernel_launch(void* const* d_in, const int* in_sizes, int n_in,
                              void* d_out, int out_size, void* d_ws, size_t ws_size,
                              hipStream_t stream) {
  const float* x  = (const float*)d_in[0];
  const float* wq = (const float*)d_in[1];
  const float* wk = (const float*)d_in[2];
  const float* wv = (const float*)d_in[3];
  const float* wo = (const float*)d_in[4];
  float* out = (float*)d_out;
  char* ws = (char*)d_ws;

  short* x_bf  = (short*)(ws);                       // 8 MB
  short* WqkvT = (short*)(ws + ((size_t)8 << 20));   // 6 MB
  short* wo_bf = (short*)(ws + ((size_t)14 << 20));  // 2 MB
  short* Qb    = (short*)(ws + ((size_t)16 << 20));  // 8 MB
  short* Kb    = (short*)(ws + ((size_t)24 << 20));  // 8 MB
  short* Vt    = (short*)(ws + ((size_t)32 << 20));  // 8 MB (V^T)
  short* Ob    = (short*)(ws + ((size_t)40 << 20));  // 8 MB

  k_cast<<<4096, 256, 0, stream>>>(x, x_bf, 1048576);
  k_cast<<<1024, 256, 0, stream>>>(wo, wo_bf, 262144);
  k_pack<<<dim3(16, 16, 3), 256, 0, stream>>>(wq, wk, wv, WqkvT);
  k_gemm<0><<<dim3(24, 32), 256, 0, stream>>>(x_bf, WqkvT, Qb, Kb, Vt, nullptr, 4096, 3072, 1024);
  k_attn<<<dim3(32, 16), 256, 0, stream>>>(Qb, Kb, Vt, Ob);
  k_gemm<1><<<dim3(8, 32), 256, 0, stream>>>(Ob, wo_bf, nullptr, nullptr, nullptr, out, 4096, 1024, 1024);
}